// Round 4
// baseline (167.502 us; speedup 1.0000x reference)
//
#include <hip/hip_runtime.h>

// GraphSAGE 2-layer: N=50000, D=128, DEG=16.
// R6: split each layer: dense GEMM ([P|Z] = feat @ [W_top|W_bot], P f32, Z bf16)
//     + pure gather kernel (out = relu(P + b + (1/16)*sum Z[nbr])).
//     Gather runs at ~100% duty in its own kernel (latency-bound fix per R5).
typedef __attribute__((ext_vector_type(8))) short short8;
typedef __attribute__((ext_vector_type(4))) float f32x4;
typedef __attribute__((ext_vector_type(2))) float f32x2;

#define N_NODES 50000
#define D 128
#define DEG 16

static __device__ __forceinline__ unsigned short f2b(float f) {
    union { float f; unsigned int u; } v; v.f = f;
    return (unsigned short)((v.u + 0x7fffu + ((v.u >> 16) & 1u)) >> 16);
}

// ---- prep ----
// blocks 0..31: pack W1,W2 ((2D,D) row-major) into fragment order for gemm_pz:
//   o = w2*4096 + kk*1024 + ct2*512 + lane*8 + e   (shorts), kk in [0,4)
//   output col c = w2*32 + 2*(lane&15) + ct2  in [0,256)
//   k_inner     = kk*32 + (lane>>4)*8 + e     in [0,128)
//   c <  128 -> P col: W[k_inner      ][c]
//   c >= 128 -> Z col: W[128 + k_inner][c-128]
// blocks 32..: x -> bf16.
__global__ void prep(const float* __restrict__ x, unsigned short* __restrict__ xb,
                     const float* __restrict__ W1, const float* __restrict__ W2,
                     unsigned short* __restrict__ Wf1, unsigned short* __restrict__ Wf2) {
    int b = blockIdx.x;
    if (b < 32) {
        int idx = b * 256 + threadIdx.x;   // 0..8191, one ushort4 per matrix
        int o   = idx * 4;
        int e0  = o & 7;                   // 0 or 4
        int l   = (o >> 3) & 63;
        int ct2 = (o >> 9) & 1;
        int kk  = (o >> 10) & 3;
        int w2  = (o >> 12) & 7;
        int c   = w2 * 32 + ((l & 15) << 1) + ct2;
        int kin = kk * 32 + (l >> 4) * 8 + e0;
        int krow = (c < 128) ? kin : 128 + kin;
        int ccol = c & 127;
        const float* s1 = W1 + krow * D + ccol;
        const float* s2 = W2 + krow * D + ccol;
        ushort4 a, cc;
        a.x  = f2b(s1[0]);     a.y  = f2b(s1[D]);
        a.z  = f2b(s1[2 * D]); a.w  = f2b(s1[3 * D]);
        *(ushort4*)(Wf1 + o) = a;
        cc.x = f2b(s2[0]);     cc.y = f2b(s2[D]);
        cc.z = f2b(s2[2 * D]); cc.w = f2b(s2[3 * D]);
        *(ushort4*)(Wf2 + o) = cc;
    } else {
        int i = ((b - 32) * 256 + threadIdx.x) * 4;
        if (i < N_NODES * D) {
            float4 v = *(const float4*)(x + i);
            ushort4 o4;
            o4.x = f2b(v.x); o4.y = f2b(v.y); o4.z = f2b(v.z); o4.w = f2b(v.w);
            *(ushort4*)(xb + i) = o4;
        }
    }
}

// ---- dense GEMM: [P | Z] = feat @ [W_top | W_bot], P f32, Z bf16 ----
// block = 256 thr, BM=32 rows; A staged via swizzled global_load_lds.
__global__ __launch_bounds__(256, 4)
void gemm_pz(const unsigned short* __restrict__ feat,   // N x D bf16
             const unsigned short* __restrict__ wf,     // fragment-packed
             float* __restrict__ P,                     // N x D f32
             unsigned short* __restrict__ Z)            // N x D bf16
{
    __shared__ __align__(16) unsigned short Al[32 * 128];  // 8 KB, XOR-swizzled
    const int tid  = threadIdx.x;
    const int row0 = blockIdx.x * 32;
    const int wave = tid >> 6;
    const int lane = tid & 63;
    const int quad = lane >> 4;
    const int l16  = lane & 15;

    // stage A: 2 x (256 lanes x 16B). LDS dest linear; source pre-swizzled so
    // that LDS[row][cb] = feat[row][cb ^ ((row&7)<<4)].
    #pragma unroll
    for (int i = 0; i < 2; ++i) {
        unsigned o    = (unsigned)tid * 16u + (unsigned)i * 4096u;
        unsigned row  = o >> 8;
        unsigned colb = o & 255u;
        unsigned scol = colb ^ ((row & 7u) << 4);
        int grow = row0 + (int)row;
        if (grow >= N_NODES) grow = N_NODES - 1;
        const char* src = (const char*)feat + (unsigned)grow * 256u + scol;
        __builtin_amdgcn_global_load_lds(
            (const __attribute__((address_space(1))) unsigned int*)src,
            (__attribute__((address_space(3))) unsigned int*)
                ((char*)Al + wave * 1024 + i * 4096),
            16, 0, 0);
    }

    // B fragments: wave covers cols [w*64, w*64+64) as col-groups w2=2w,2w+1
    short8 bfrag[4][4];
    #pragma unroll
    for (int kk = 0; kk < 4; ++kk)
        #pragma unroll
        for (int ct = 0; ct < 4; ++ct) {
            int w2 = 2 * wave + (ct >> 1), ct2 = ct & 1;
            bfrag[kk][ct] = *(const short8*)(wf + w2 * 4096 + kk * 1024 + ct2 * 512 + lane * 8);
        }

    __syncthreads();   // drains global_load_lds (vmcnt) before ds_read

    f32x4 acc[2][4];
    #pragma unroll
    for (int rt = 0; rt < 2; ++rt)
        #pragma unroll
        for (int ct = 0; ct < 4; ++ct)
            acc[rt][ct] = (f32x4){0.f, 0.f, 0.f, 0.f};

    #pragma unroll
    for (int kk = 0; kk < 4; ++kk) {
        short8 af[2];
        #pragma unroll
        for (int rt = 0; rt < 2; ++rt) {
            unsigned row  = (unsigned)(rt * 16 + l16);
            unsigned byte = row * 256u + (unsigned)kk * 64u + (unsigned)quad * 16u;
            byte ^= (row & 7u) << 4;
            af[rt] = *(const short8*)((const char*)Al + byte);
        }
        #pragma unroll
        for (int rt = 0; rt < 2; ++rt)
            #pragma unroll
            for (int ct = 0; ct < 4; ++ct)
                acc[rt][ct] = __builtin_amdgcn_mfma_f32_16x16x32_bf16(
                    af[rt], bfrag[kk][ct], acc[rt][ct], 0, 0, 0);
    }

    // epilogue: adjacent col pairs; waves 0,1 -> P (f32x2), waves 2,3 -> Z (bf16x2)
    #pragma unroll
    for (int ctp = 0; ctp < 2; ++ctp) {
        int c0 = (2 * wave + ctp) * 32 + (l16 << 1);
        #pragma unroll
        for (int rt = 0; rt < 2; ++rt) {
            int gb = row0 + rt * 16 + quad * 4;
            #pragma unroll
            for (int r = 0; r < 4; ++r) {
                int grow = gb + r;
                if (grow >= N_NODES) continue;
                float v0 = acc[rt][2 * ctp][r];
                float v1 = acc[rt][2 * ctp + 1][r];
                if (c0 < 128) {
                    f32x2 o2; o2.x = v0; o2.y = v1;
                    *(f32x2*)(P + grow * D + c0) = o2;
                } else {
                    unsigned u = (unsigned)f2b(v0) | ((unsigned)f2b(v1) << 16);
                    *(unsigned*)(Z + grow * D + (c0 - 128)) = u;
                }
            }
        }
    }
}

// ---- gather: out = relu( P + b + (1/16) * sum_j Z[nbr_j] ) ----
// block = 256 thr = 16 rows x 16 slices; 3125 blocks (N%16==0, no tail).
template <int OUT_BF16>
__global__ __launch_bounds__(256, 4)
void agg(const unsigned short* __restrict__ Z,   // N x D bf16
         const float* __restrict__ P,            // N x D f32
         const int* __restrict__ nbr,            // N x DEG
         const float* __restrict__ bias,         // D f32
         void* __restrict__ out)
{
    __shared__ __align__(16) int Nl[256];
    const int tid  = threadIdx.x;
    const int row0 = blockIdx.x << 4;
    Nl[tid] = nbr[(row0 << 4) + tid];
    __syncthreads();

    const int r = tid >> 4, s = tid & 15;
    const int grow = row0 + r;
    const char* zb = (const char*)Z;
    const unsigned sB = (unsigned)s << 4;

    int4 i0 = *(const int4*)(Nl + r * 16);
    int4 i1 = *(const int4*)(Nl + r * 16 + 4);
    int4 i2 = *(const int4*)(Nl + r * 16 + 8);
    int4 i3 = *(const int4*)(Nl + r * 16 + 12);
    int ids[16] = { i0.x, i0.y, i0.z, i0.w, i1.x, i1.y, i1.z, i1.w,
                    i2.x, i2.y, i2.z, i2.w, i3.x, i3.y, i3.z, i3.w };

    short8 v[16];
    #pragma unroll
    for (int j = 0; j < 16; ++j)
        v[j] = *(const short8*)(zb + (((unsigned)ids[j]) << 8) + sB);

    f32x2 am[4];
    #pragma unroll
    for (int i = 0; i < 4; ++i) am[i] = (f32x2){0.f, 0.f};
    #pragma unroll
    for (int j = 0; j < 16; ++j) {
        union { short8 s8; unsigned u[4]; } vv; vv.s8 = v[j];
        #pragma unroll
        for (int i = 0; i < 4; ++i) {
            unsigned ui = vv.u[i];
            f32x2 e;
            e.x = __uint_as_float(ui << 16);          // dim 2i
            e.y = __uint_as_float(ui & 0xffff0000u);  // dim 2i+1
            am[i] += e;
        }
    }

    f32x4 p0 = *(const f32x4*)(P + grow * D + s * 8);
    f32x4 p1 = *(const f32x4*)(P + grow * D + s * 8 + 4);
    f32x4 b0 = *(const f32x4*)(bias + s * 8);
    f32x4 b1 = *(const f32x4*)(bias + s * 8 + 4);

    float o[8];
    o[0] = p0.x + b0.x + am[0].x * 0.0625f;
    o[1] = p0.y + b0.y + am[0].y * 0.0625f;
    o[2] = p0.z + b0.z + am[1].x * 0.0625f;
    o[3] = p0.w + b0.w + am[1].y * 0.0625f;
    o[4] = p1.x + b1.x + am[2].x * 0.0625f;
    o[5] = p1.y + b1.y + am[2].y * 0.0625f;
    o[6] = p1.z + b1.z + am[3].x * 0.0625f;
    o[7] = p1.w + b1.w + am[3].y * 0.0625f;
    #pragma unroll
    for (int i = 0; i < 8; ++i) o[i] = o[i] > 0.f ? o[i] : 0.f;

    if (OUT_BF16) {
        union { unsigned short u[8]; short8 s8; } m;
        #pragma unroll
        for (int i = 0; i < 8; ++i) m.u[i] = f2b(o[i]);
        *(short8*)((unsigned short*)out + grow * D + s * 8) = m.s8;
    } else {
        f32x4 q0; q0.x = o[0]; q0.y = o[1]; q0.z = o[2]; q0.w = o[3];
        f32x4 q1; q1.x = o[4]; q1.y = o[5]; q1.z = o[6]; q1.w = o[7];
        *(f32x4*)((float*)out + grow * D + s * 8) = q0;
        *(f32x4*)((float*)out + grow * D + s * 8 + 4) = q1;
    }
}

extern "C" void kernel_launch(void* const* d_in, const int* in_sizes, int n_in,
                              void* d_out, int out_size, void* d_ws, size_t ws_size,
                              hipStream_t stream) {
    const float* x  = (const float*)d_in[0];
    const int*   nb = (const int*)d_in[1];
    const float* W1 = (const float*)d_in[2];
    const float* b1 = (const float*)d_in[3];
    const float* W2 = (const float*)d_in[4];
    const float* b2 = (const float*)d_in[5];

    char* ws = (char*)d_ws;
    unsigned short* Wf1 = (unsigned short*)(ws);                        // 64 KB
    unsigned short* Wf2 = (unsigned short*)(ws + 65536);                // 64 KB
    unsigned short* xb  = (unsigned short*)(ws + 131072);               // 12.8 MB
    unsigned short* h1  = (unsigned short*)(ws + 131072 + 12800000);    // 12.8 MB
    unsigned short* Zb  = (unsigned short*)(ws + 131072 + 25600000);    // 12.8 MB
    float*          Pb  = (float*)(ws + 131072 + 38400000);             // 25.6 MB

    prep<<<32 + 6250, 256, 0, stream>>>(x, xb, W1, W2, Wf1, Wf2);

    const int ggrid = (N_NODES + 31) / 32;   // 1563
    const int agrid = N_NODES / 16;          // 3125

    gemm_pz<<<ggrid, 256, 0, stream>>>(xb, Wf1, Pb, Zb);
    agg<1><<<agrid, 256, 0, stream>>>(Zb, Pb, nb, b1, h1);
    gemm_pz<<<ggrid, 256, 0, stream>>>(h1, Wf2, Pb, Zb);
    agg<0><<<agrid, 256, 0, stream>>>(Zb, Pb, nb, b2, d_out);
}